// Round 1
// baseline (1034.813 us; speedup 1.0000x reference)
//
#include <hip/hip_runtime.h>
#include <hip/hip_bf16.h>

#define T_TOK 4096
#define DIM   1024
#define FDIM  4096
#define NEXP  8
#define BM    128
#define BN    128
#define BK    32

typedef __attribute__((ext_vector_type(8))) short bf16x8_t;   // 8 bf16 = 4 VGPR
typedef __attribute__((ext_vector_type(4))) float f32x4_t;    // MFMA C/D

__device__ __forceinline__ unsigned short f2bf(float f) {
    union { __hip_bfloat16 h; unsigned short u; } c;
    c.h = __float2bfloat16(f);
    return c.u;
}

// ---------------------------------------------------------------------------
// 1. Gate: one wave per token. fp32 logits, top-2, renormalized weights.
//    Appends (token, weight) to per-expert lists via atomic counters.
// ---------------------------------------------------------------------------
__global__ __launch_bounds__(256) void gate_kernel(
    const float* __restrict__ x, const float* __restrict__ gw,
    const float* __restrict__ gb, int* __restrict__ cnt,
    int* __restrict__ toklist, float* __restrict__ wlist)
{
    const int lane = threadIdx.x & 63;
    const int wv   = threadIdx.x >> 6;
    const int t    = blockIdx.x * 4 + wv;
    const float* xr = x + (size_t)t * DIM;

    float4 xv[4];
#pragma unroll
    for (int c = 0; c < 4; ++c)
        xv[c] = *reinterpret_cast<const float4*>(xr + c * 256 + lane * 4);

    float logit[NEXP];
#pragma unroll
    for (int e = 0; e < NEXP; ++e) {
        const float* gr = gw + e * DIM;
        float s = 0.f;
#pragma unroll
        for (int c = 0; c < 4; ++c) {
            float4 g = *reinterpret_cast<const float4*>(gr + c * 256 + lane * 4);
            s += xv[c].x * g.x + xv[c].y * g.y + xv[c].z * g.z + xv[c].w * g.w;
        }
#pragma unroll
        for (int o = 32; o > 0; o >>= 1) s += __shfl_xor(s, o, 64);
        logit[e] = s + gb[e];
    }

    if (lane == 0) {
        int i1 = 0;
#pragma unroll
        for (int e = 1; e < NEXP; ++e) if (logit[e] > logit[i1]) i1 = e;
        int i2 = (i1 == 0) ? 1 : 0;
#pragma unroll
        for (int e = 0; e < NEXP; ++e)
            if (e != i1 && e != i2 && logit[e] > logit[i2]) i2 = e;
        // softmax -> top2 -> renorm == 2-way softmax over the two logits
        float eb = expf(logit[i2] - logit[i1]);   // l[i1] is the max
        float wA = 1.f / (1.f + eb);
        float wB = eb / (1.f + eb);
        int p = atomicAdd(&cnt[i1], 1);
        toklist[i1 * T_TOK + p] = t; wlist[i1 * T_TOK + p] = wA;
        p = atomicAdd(&cnt[i2], 1);
        toklist[i2 * T_TOK + p] = t; wlist[i2 * T_TOK + p] = wB;
    }
}

// ---------------------------------------------------------------------------
// 2. 128-aligned exclusive prefix of per-expert counts (8 entries -> 1 thread)
// ---------------------------------------------------------------------------
__global__ void offsets_kernel(const int* __restrict__ cnt, int* __restrict__ offs)
{
    if (threadIdx.x == 0) {
        int o = 0;
#pragma unroll
        for (int e = 0; e < NEXP; ++e) {
            offs[e] = o;
            o += ((cnt[e] + BM - 1) / BM) * BM;
        }
    }
}

// ---------------------------------------------------------------------------
// 3. Gather: Xp[slot] = bf16(x[token]); zero-fill tile padding rows.
//    One block per candidate row, 256 thr * 4 elem = 1024 = D.
// ---------------------------------------------------------------------------
__global__ __launch_bounds__(256) void gather_kernel(
    const float* __restrict__ x, const int* __restrict__ cnt,
    const int* __restrict__ offs, const int* __restrict__ toklist,
    unsigned short* __restrict__ Xp)
{
    const int b = blockIdx.x;
    const int e = b >> 12;          // / T_TOK
    const int i = b & 4095;
    const int c  = cnt[e];
    const int ca = ((c + BM - 1) >> 7) << 7;
    if (i >= ca) return;
    unsigned short* dst = Xp + (size_t)(offs[e] + i) * DIM;
    const int t4 = threadIdx.x * 4;
    ushort4 o;
    if (i < c) {
        const float* src = x + (size_t)toklist[e * T_TOK + i] * DIM;
        float4 v = *reinterpret_cast<const float4*>(src + t4);
        o.x = f2bf(v.x); o.y = f2bf(v.y); o.z = f2bf(v.z); o.w = f2bf(v.w);
    } else {
        o.x = 0; o.y = 0; o.z = 0; o.w = 0;
    }
    *reinterpret_cast<ushort4*>(dst + t4) = o;
}

// ---------------------------------------------------------------------------
// 4. Stage A: fused h1/h3 GEMM + SwiGLU epilogue -> act (bf16)
//    C[m,f] over A=Xp[slot,1024](bf16), B=w1/w3[e][f,1024](fp32, cvt in stage)
//    128x128 tile, BK=32, 4 waves each 64x64, 16x16x32 bf16 MFMA.
// ---------------------------------------------------------------------------
__global__ __launch_bounds__(256, 2) void stageA_kernel(
    const unsigned short* __restrict__ Xp, const float* __restrict__ w1,
    const float* __restrict__ w3, const int* __restrict__ cnt,
    const int* __restrict__ offs, unsigned short* __restrict__ act)
{
    const int e  = blockIdx.z;
    const int c  = cnt[e];
    const int mt = blockIdx.y;
    if (mt * BM >= c) return;
    const int nt = blockIdx.x;
    const size_t slot0 = (size_t)offs[e] + (size_t)mt * BM;
    const int n0 = nt * BN;

    __shared__ __align__(16) unsigned short As[BM * BK];
    __shared__ __align__(16) unsigned short B1s[BN * BK];
    __shared__ __align__(16) unsigned short B3s[BN * BK];

    const int tid  = threadIdx.x;
    const int lane = tid & 63;
    const int wv   = tid >> 6;
    const int wm   = (wv & 1) * 64;
    const int wn   = (wv >> 1) * 64;
    const int quad = lane >> 4;
    const int r    = lane & 15;

    const int srow = tid >> 1;          // 0..127
    const int scol = (tid & 1) * 16;    // 0 or 16

    const unsigned short* Ag = Xp + (slot0 + srow) * DIM + scol;
    const float* B1g = w1 + ((size_t)e * FDIM + n0 + srow) * DIM + scol;
    const float* B3g = w3 + ((size_t)e * FDIM + n0 + srow) * DIM + scol;
    unsigned short* Asw = As  + srow * BK + scol;
    unsigned short* B1w = B1s + srow * BK + scol;
    unsigned short* B3w = B3s + srow * BK + scol;

    f32x4_t acc1[4][4];
    f32x4_t acc3[4][4];
#pragma unroll
    for (int i = 0; i < 4; ++i)
#pragma unroll
        for (int j = 0; j < 4; ++j) {
            acc1[i][j] = (f32x4_t){0.f, 0.f, 0.f, 0.f};
            acc3[i][j] = (f32x4_t){0.f, 0.f, 0.f, 0.f};
        }

    for (int k0 = 0; k0 < DIM; k0 += BK) {
        __syncthreads();
        uint4  a0  = *reinterpret_cast<const uint4*>(Ag + k0);
        uint4  a1  = *reinterpret_cast<const uint4*>(Ag + k0 + 8);
        float4 b10 = *reinterpret_cast<const float4*>(B1g + k0);
        float4 b11 = *reinterpret_cast<const float4*>(B1g + k0 + 4);
        float4 b12 = *reinterpret_cast<const float4*>(B1g + k0 + 8);
        float4 b13 = *reinterpret_cast<const float4*>(B1g + k0 + 12);
        float4 b30 = *reinterpret_cast<const float4*>(B3g + k0);
        float4 b31 = *reinterpret_cast<const float4*>(B3g + k0 + 4);
        float4 b32 = *reinterpret_cast<const float4*>(B3g + k0 + 8);
        float4 b33 = *reinterpret_cast<const float4*>(B3g + k0 + 12);

        *reinterpret_cast<uint4*>(Asw)     = a0;
        *reinterpret_cast<uint4*>(Asw + 8) = a1;
        ushort4 q;
        q.x = f2bf(b10.x); q.y = f2bf(b10.y); q.z = f2bf(b10.z); q.w = f2bf(b10.w);
        *reinterpret_cast<ushort4*>(B1w)      = q;
        q.x = f2bf(b11.x); q.y = f2bf(b11.y); q.z = f2bf(b11.z); q.w = f2bf(b11.w);
        *reinterpret_cast<ushort4*>(B1w + 4)  = q;
        q.x = f2bf(b12.x); q.y = f2bf(b12.y); q.z = f2bf(b12.z); q.w = f2bf(b12.w);
        *reinterpret_cast<ushort4*>(B1w + 8)  = q;
        q.x = f2bf(b13.x); q.y = f2bf(b13.y); q.z = f2bf(b13.z); q.w = f2bf(b13.w);
        *reinterpret_cast<ushort4*>(B1w + 12) = q;
        q.x = f2bf(b30.x); q.y = f2bf(b30.y); q.z = f2bf(b30.z); q.w = f2bf(b30.w);
        *reinterpret_cast<ushort4*>(B3w)      = q;
        q.x = f2bf(b31.x); q.y = f2bf(b31.y); q.z = f2bf(b31.z); q.w = f2bf(b31.w);
        *reinterpret_cast<ushort4*>(B3w + 4)  = q;
        q.x = f2bf(b32.x); q.y = f2bf(b32.y); q.z = f2bf(b32.z); q.w = f2bf(b32.w);
        *reinterpret_cast<ushort4*>(B3w + 8)  = q;
        q.x = f2bf(b33.x); q.y = f2bf(b33.y); q.z = f2bf(b33.z); q.w = f2bf(b33.w);
        *reinterpret_cast<ushort4*>(B3w + 12) = q;
        __syncthreads();

        bf16x8_t af[4];
#pragma unroll
        for (int i = 0; i < 4; ++i)
            af[i] = *reinterpret_cast<const bf16x8_t*>(As + (wm + i * 16 + r) * BK + quad * 8);
#pragma unroll
        for (int j = 0; j < 4; ++j) {
            bf16x8_t b1 = *reinterpret_cast<const bf16x8_t*>(B1s + (wn + j * 16 + r) * BK + quad * 8);
            bf16x8_t b3 = *reinterpret_cast<const bf16x8_t*>(B3s + (wn + j * 16 + r) * BK + quad * 8);
#pragma unroll
            for (int i = 0; i < 4; ++i) {
                acc1[i][j] = __builtin_amdgcn_mfma_f32_16x16x32_bf16(af[i], b1, acc1[i][j], 0, 0, 0);
                acc3[i][j] = __builtin_amdgcn_mfma_f32_16x16x32_bf16(af[i], b3, acc3[i][j], 0, 0, 0);
            }
        }
    }

    // epilogue: act = silu(h1) * h3, bf16 store
    unsigned short* abase = act + slot0 * FDIM + n0;
#pragma unroll
    for (int i = 0; i < 4; ++i)
#pragma unroll
        for (int j = 0; j < 4; ++j)
#pragma unroll
            for (int rr = 0; rr < 4; ++rr) {
                int m = wm + i * 16 + quad * 4 + rr;
                int n = wn + j * 16 + r;
                float h1 = acc1[i][j][rr];
                float h3 = acc3[i][j][rr];
                float sw = h1 / (1.f + __expf(-h1)) * h3;
                abase[(size_t)m * FDIM + n] = f2bf(sw);
            }
}

// ---------------------------------------------------------------------------
// 5. Stage B: out[tok] += cw * (act[slot] @ w2[e]^T)
// ---------------------------------------------------------------------------
__global__ __launch_bounds__(256, 2) void stageB_kernel(
    const unsigned short* __restrict__ act, const float* __restrict__ w2,
    const int* __restrict__ cnt, const int* __restrict__ offs,
    const int* __restrict__ toklist, const float* __restrict__ wlist,
    float* __restrict__ out)
{
    const int e  = blockIdx.z;
    const int c  = cnt[e];
    const int mt = blockIdx.y;
    if (mt * BM >= c) return;
    const int nt = blockIdx.x;              // 0..7 (D/128)
    const size_t slot0 = (size_t)offs[e] + (size_t)mt * BM;
    const int n0 = nt * BN;

    __shared__ __align__(16) unsigned short As[BM * BK];
    __shared__ __align__(16) unsigned short Bs[BN * BK];

    const int tid  = threadIdx.x;
    const int lane = tid & 63;
    const int wv   = tid >> 6;
    const int wm   = (wv & 1) * 64;
    const int wn   = (wv >> 1) * 64;
    const int quad = lane >> 4;
    const int r    = lane & 15;

    const int srow = tid >> 1;
    const int scol = (tid & 1) * 16;

    const unsigned short* Ag = act + (slot0 + srow) * FDIM + scol;
    const float* Bg = w2 + ((size_t)e * DIM + n0 + srow) * FDIM + scol;
    unsigned short* Asw = As + srow * BK + scol;
    unsigned short* Bw  = Bs + srow * BK + scol;

    f32x4_t acc[4][4];
#pragma unroll
    for (int i = 0; i < 4; ++i)
#pragma unroll
        for (int j = 0; j < 4; ++j) acc[i][j] = (f32x4_t){0.f, 0.f, 0.f, 0.f};

    for (int k0 = 0; k0 < FDIM; k0 += BK) {
        __syncthreads();
        uint4  a0 = *reinterpret_cast<const uint4*>(Ag + k0);
        uint4  a1 = *reinterpret_cast<const uint4*>(Ag + k0 + 8);
        float4 f0 = *reinterpret_cast<const float4*>(Bg + k0);
        float4 f1 = *reinterpret_cast<const float4*>(Bg + k0 + 4);
        float4 f2 = *reinterpret_cast<const float4*>(Bg + k0 + 8);
        float4 f3 = *reinterpret_cast<const float4*>(Bg + k0 + 12);

        *reinterpret_cast<uint4*>(Asw)     = a0;
        *reinterpret_cast<uint4*>(Asw + 8) = a1;
        ushort4 q;
        q.x = f2bf(f0.x); q.y = f2bf(f0.y); q.z = f2bf(f0.z); q.w = f2bf(f0.w);
        *reinterpret_cast<ushort4*>(Bw)      = q;
        q.x = f2bf(f1.x); q.y = f2bf(f1.y); q.z = f2bf(f1.z); q.w = f2bf(f1.w);
        *reinterpret_cast<ushort4*>(Bw + 4)  = q;
        q.x = f2bf(f2.x); q.y = f2bf(f2.y); q.z = f2bf(f2.z); q.w = f2bf(f2.w);
        *reinterpret_cast<ushort4*>(Bw + 8)  = q;
        q.x = f2bf(f3.x); q.y = f2bf(f3.y); q.z = f2bf(f3.z); q.w = f2bf(f3.w);
        *reinterpret_cast<ushort4*>(Bw + 12) = q;
        __syncthreads();

        bf16x8_t af[4];
#pragma unroll
        for (int i = 0; i < 4; ++i)
            af[i] = *reinterpret_cast<const bf16x8_t*>(As + (wm + i * 16 + r) * BK + quad * 8);
#pragma unroll
        for (int j = 0; j < 4; ++j) {
            bf16x8_t bf = *reinterpret_cast<const bf16x8_t*>(Bs + (wn + j * 16 + r) * BK + quad * 8);
#pragma unroll
            for (int i = 0; i < 4; ++i)
                acc[i][j] = __builtin_amdgcn_mfma_f32_16x16x32_bf16(af[i], bf, acc[i][j], 0, 0, 0);
        }
    }

    // epilogue: scale by combine weight, atomicAdd into out (2 adds/element, commutative)
    const int row0 = mt * BM;
#pragma unroll
    for (int i = 0; i < 4; ++i)
#pragma unroll
        for (int rr = 0; rr < 4; ++rr) {
            int m = wm + i * 16 + quad * 4 + rr;
            int row = row0 + m;
            if (row < c) {
                int tok  = toklist[e * T_TOK + row];
                float wt = wlist[e * T_TOK + row];
                float* orow = out + (size_t)tok * DIM + n0;
#pragma unroll
                for (int j = 0; j < 4; ++j) {
                    int n = wn + j * 16 + r;
                    atomicAdd(&orow[n], wt * acc[i][j][rr]);
                }
            }
        }
}

// ---------------------------------------------------------------------------
extern "C" void kernel_launch(void* const* d_in, const int* in_sizes, int n_in,
                              void* d_out, int out_size, void* d_ws, size_t ws_size,
                              hipStream_t stream)
{
    (void)in_sizes; (void)n_in; (void)out_size; (void)ws_size;
    const float* x  = (const float*)d_in[0];
    const float* gw = (const float*)d_in[1];
    const float* gb = (const float*)d_in[2];
    const float* w1 = (const float*)d_in[3];
    const float* w3 = (const float*)d_in[4];
    const float* w2 = (const float*)d_in[5];
    float* out = (float*)d_out;

    // workspace layout (~94.6 MB)
    char* ws = (char*)d_ws;
    unsigned short* Xp  = (unsigned short*)ws;                       // 9216*1024*2 = 18,874,368
    unsigned short* act = (unsigned short*)(ws + 18874368);          // 9216*4096*2 = 75,497,472
    int*   cnt     = (int*)(ws + 18874368 + 75497472);               // 8 ints (pad 256B)
    int*   offs    = cnt + 64;                                       // 8 ints
    int*   toklist = cnt + 128;                                      // 8*4096 ints
    float* wlist   = (float*)(cnt + 128 + NEXP * T_TOK);             // 8*4096 floats

    hipMemsetAsync(cnt, 0, 64, stream);
    hipMemsetAsync(out, 0, (size_t)T_TOK * DIM * sizeof(float), stream);

    gate_kernel<<<T_TOK / 4, 256, 0, stream>>>(x, gw, gb, cnt, toklist, wlist);
    offsets_kernel<<<1, 64, 0, stream>>>(cnt, offs);
    gather_kernel<<<NEXP * T_TOK, 256, 0, stream>>>(x, cnt, offs, toklist, Xp);
    stageA_kernel<<<dim3(FDIM / BN, T_TOK / BM, NEXP), 256, 0, stream>>>(Xp, w1, w3, cnt, offs, act);
    stageB_kernel<<<dim3(DIM / BN, T_TOK / BM, NEXP), 256, 0, stream>>>(act, w2, cnt, offs, toklist, wlist, out);
}

// Round 2
// 879.953 us; speedup vs baseline: 1.1760x; 1.1760x over previous
//
#include <hip/hip_runtime.h>
#include <hip/hip_bf16.h>

#define T_TOK 4096
#define DIM   1024
#define FDIM  4096
#define NEXP  8
#define BM    128
#define BN    64
#define BK    32
#define LDP   40   // padded LDS row stride (elements): 80B -> conflict-free-ish

typedef __attribute__((ext_vector_type(8))) short bf16x8_t;   // 8 bf16 = 4 VGPR
typedef __attribute__((ext_vector_type(4))) float f32x4_t;    // MFMA C/D

__device__ __forceinline__ unsigned short f2bf(float f) {
    union { __hip_bfloat16 h; unsigned short u; } c;
    c.h = __float2bfloat16(f);
    return c.u;
}
__device__ __forceinline__ ushort4 cvt8(const float4& a, const float4& b) {
    ushort4 q; // packs only 4 -- helper for 4 floats
    q.x = f2bf(a.x); q.y = f2bf(a.y); q.z = f2bf(a.z); q.w = f2bf(a.w);
    (void)b; return q;
}

// ---------------------------------------------------------------------------
// 1. Gate: one wave per token. fp32 logits, top-2, renormalized weights.
// ---------------------------------------------------------------------------
__global__ __launch_bounds__(256) void gate_kernel(
    const float* __restrict__ x, const float* __restrict__ gw,
    const float* __restrict__ gb, int* __restrict__ cnt,
    int* __restrict__ toklist, float* __restrict__ wlist)
{
    const int lane = threadIdx.x & 63;
    const int wv   = threadIdx.x >> 6;
    const int t    = blockIdx.x * 4 + wv;
    const float* xr = x + (size_t)t * DIM;

    float4 xv[4];
#pragma unroll
    for (int c = 0; c < 4; ++c)
        xv[c] = *reinterpret_cast<const float4*>(xr + c * 256 + lane * 4);

    float logit[NEXP];
#pragma unroll
    for (int e = 0; e < NEXP; ++e) {
        const float* gr = gw + e * DIM;
        float s = 0.f;
#pragma unroll
        for (int c = 0; c < 4; ++c) {
            float4 g = *reinterpret_cast<const float4*>(gr + c * 256 + lane * 4);
            s += xv[c].x * g.x + xv[c].y * g.y + xv[c].z * g.z + xv[c].w * g.w;
        }
#pragma unroll
        for (int o = 32; o > 0; o >>= 1) s += __shfl_xor(s, o, 64);
        logit[e] = s + gb[e];
    }

    if (lane == 0) {
        int i1 = 0;
#pragma unroll
        for (int e = 1; e < NEXP; ++e) if (logit[e] > logit[i1]) i1 = e;
        int i2 = (i1 == 0) ? 1 : 0;
#pragma unroll
        for (int e = 0; e < NEXP; ++e)
            if (e != i1 && e != i2 && logit[e] > logit[i2]) i2 = e;
        float eb = expf(logit[i2] - logit[i1]);
        float wA = 1.f / (1.f + eb);
        float wB = eb / (1.f + eb);
        int p = atomicAdd(&cnt[i1], 1);
        toklist[i1 * T_TOK + p] = t; wlist[i1 * T_TOK + p] = wA;
        p = atomicAdd(&cnt[i2], 1);
        toklist[i2 * T_TOK + p] = t; wlist[i2 * T_TOK + p] = wB;
    }
}

// ---------------------------------------------------------------------------
// 2. 128-aligned exclusive prefix of per-expert counts
// ---------------------------------------------------------------------------
__global__ void offsets_kernel(const int* __restrict__ cnt, int* __restrict__ offs)
{
    if (threadIdx.x == 0) {
        int o = 0;
#pragma unroll
        for (int e = 0; e < NEXP; ++e) {
            offs[e] = o;
            o += ((cnt[e] + BM - 1) / BM) * BM;
        }
    }
}

// ---------------------------------------------------------------------------
// 3. Gather: Xp[slot] = bf16(x[token]); zero-fill tile padding rows.
// ---------------------------------------------------------------------------
__global__ __launch_bounds__(256) void gather_kernel(
    const float* __restrict__ x, const int* __restrict__ cnt,
    const int* __restrict__ offs, const int* __restrict__ toklist,
    unsigned short* __restrict__ Xp)
{
    const int b = blockIdx.x;
    const int e = b >> 12;
    const int i = b & 4095;
    const int c  = cnt[e];
    const int ca = ((c + BM - 1) >> 7) << 7;
    if (i >= ca) return;
    unsigned short* dst = Xp + (size_t)(offs[e] + i) * DIM;
    const int t4 = threadIdx.x * 4;
    ushort4 o;
    if (i < c) {
        const float* src = x + (size_t)toklist[e * T_TOK + i] * DIM;
        float4 v = *reinterpret_cast<const float4*>(src + t4);
        o.x = f2bf(v.x); o.y = f2bf(v.y); o.z = f2bf(v.z); o.w = f2bf(v.w);
    } else {
        o.x = 0; o.y = 0; o.z = 0; o.w = 0;
    }
    *reinterpret_cast<ushort4*>(dst + t4) = o;
}

// ---------------------------------------------------------------------------
// 4. Stage A: fused h1/h3 GEMM + SwiGLU -> act (bf16)
//    128x64 tile, BK=32, software-pipelined staging (prefetch k+1 regs).
//    4 waves, each 64x32 output per matrix.
// ---------------------------------------------------------------------------
__global__ __launch_bounds__(256, 3) void stageA_kernel(
    const unsigned short* __restrict__ Xp, const float* __restrict__ w1,
    const float* __restrict__ w3, const int* __restrict__ cnt,
    const int* __restrict__ offs, unsigned short* __restrict__ act)
{
    const int e  = blockIdx.z;
    const int c  = cnt[e];
    const int mt = blockIdx.y;
    if (mt * BM >= c) return;
    const int nt = blockIdx.x;
    const size_t slot0 = (size_t)offs[e] + (size_t)mt * BM;
    const int n0 = nt * BN;

    __shared__ __align__(16) unsigned short As[BM * LDP];
    __shared__ __align__(16) unsigned short B1s[BN * LDP];
    __shared__ __align__(16) unsigned short B3s[BN * LDP];

    const int tid  = threadIdx.x;
    const int lane = tid & 63;
    const int wv   = tid >> 6;
    const int wm   = (wv & 1) * 64;
    const int wn   = (wv >> 1) * 32;
    const int quad = lane >> 4;
    const int r    = lane & 15;

    // A staging: thread -> row tid>>1 (0..127), 16B half (tid&1)
    const int arow = tid >> 1;
    const int acol = (tid & 1) * 16;
    const unsigned short* Ag = Xp + (slot0 + arow) * DIM + acol;
    unsigned short* Asw = As + arow * LDP + acol;
    // B staging: thread -> row tid>>2 (0..63), 8-col group (tid&3)*8
    const int brow = tid >> 2;
    const int bcol = (tid & 3) * 8;
    const float* B1g = w1 + ((size_t)e * FDIM + n0 + brow) * DIM + bcol;
    const float* B3g = w3 + ((size_t)e * FDIM + n0 + brow) * DIM + bcol;
    unsigned short* B1w = B1s + brow * LDP + bcol;
    unsigned short* B3w = B3s + brow * LDP + bcol;

    f32x4_t acc1[4][2];
    f32x4_t acc3[4][2];
#pragma unroll
    for (int i = 0; i < 4; ++i)
#pragma unroll
        for (int j = 0; j < 2; ++j) {
            acc1[i][j] = (f32x4_t){0.f, 0.f, 0.f, 0.f};
            acc3[i][j] = (f32x4_t){0.f, 0.f, 0.f, 0.f};
        }

    // prologue: load k-tile 0 into regs
    uint4  a0 = *reinterpret_cast<const uint4*>(Ag);
    uint4  a1 = *reinterpret_cast<const uint4*>(Ag + 8);
    float4 p10 = *reinterpret_cast<const float4*>(B1g);
    float4 p11 = *reinterpret_cast<const float4*>(B1g + 4);
    float4 p30 = *reinterpret_cast<const float4*>(B3g);
    float4 p31 = *reinterpret_cast<const float4*>(B3g + 4);

    for (int k0 = 0; k0 < DIM; k0 += BK) {
        // write current regs -> LDS (cvt for B)
        *reinterpret_cast<uint4*>(Asw)     = a0;
        *reinterpret_cast<uint4*>(Asw + 8) = a1;
        ushort4 q;
        q.x = f2bf(p10.x); q.y = f2bf(p10.y); q.z = f2bf(p10.z); q.w = f2bf(p10.w);
        *reinterpret_cast<ushort4*>(B1w)     = q;
        q.x = f2bf(p11.x); q.y = f2bf(p11.y); q.z = f2bf(p11.z); q.w = f2bf(p11.w);
        *reinterpret_cast<ushort4*>(B1w + 4) = q;
        q.x = f2bf(p30.x); q.y = f2bf(p30.y); q.z = f2bf(p30.z); q.w = f2bf(p30.w);
        *reinterpret_cast<ushort4*>(B3w)     = q;
        q.x = f2bf(p31.x); q.y = f2bf(p31.y); q.z = f2bf(p31.z); q.w = f2bf(p31.w);
        *reinterpret_cast<ushort4*>(B3w + 4) = q;
        __syncthreads();

        // issue next tile's global loads (overlap with MFMA below)
        if (k0 + BK < DIM) {
            a0  = *reinterpret_cast<const uint4*>(Ag + k0 + BK);
            a1  = *reinterpret_cast<const uint4*>(Ag + k0 + BK + 8);
            p10 = *reinterpret_cast<const float4*>(B1g + k0 + BK);
            p11 = *reinterpret_cast<const float4*>(B1g + k0 + BK + 4);
            p30 = *reinterpret_cast<const float4*>(B3g + k0 + BK);
            p31 = *reinterpret_cast<const float4*>(B3g + k0 + BK + 4);
        }

        bf16x8_t af[4];
#pragma unroll
        for (int i = 0; i < 4; ++i)
            af[i] = *reinterpret_cast<const bf16x8_t*>(As + (wm + i * 16 + r) * LDP + quad * 8);
#pragma unroll
        for (int j = 0; j < 2; ++j) {
            bf16x8_t b1 = *reinterpret_cast<const bf16x8_t*>(B1s + (wn + j * 16 + r) * LDP + quad * 8);
            bf16x8_t b3 = *reinterpret_cast<const bf16x8_t*>(B3s + (wn + j * 16 + r) * LDP + quad * 8);
#pragma unroll
            for (int i = 0; i < 4; ++i) {
                acc1[i][j] = __builtin_amdgcn_mfma_f32_16x16x32_bf16(af[i], b1, acc1[i][j], 0, 0, 0);
                acc3[i][j] = __builtin_amdgcn_mfma_f32_16x16x32_bf16(af[i], b3, acc3[i][j], 0, 0, 0);
            }
        }
        __syncthreads();
    }

    unsigned short* abase = act + slot0 * FDIM + n0;
#pragma unroll
    for (int i = 0; i < 4; ++i)
#pragma unroll
        for (int j = 0; j < 2; ++j)
#pragma unroll
            for (int rr = 0; rr < 4; ++rr) {
                int m = wm + i * 16 + quad * 4 + rr;
                int n = wn + j * 16 + r;
                float h1 = acc1[i][j][rr];
                float h3 = acc3[i][j][rr];
                float sw = h1 / (1.f + __expf(-h1)) * h3;
                abase[(size_t)m * FDIM + n] = f2bf(sw);
            }
}

// ---------------------------------------------------------------------------
// 5. Stage B: out[tok] += cw * (act[slot] @ w2[e]^T), pipelined like stage A.
//    128x64 tile, 4 waves each 64x32.
// ---------------------------------------------------------------------------
__global__ __launch_bounds__(256, 4) void stageB_kernel(
    const unsigned short* __restrict__ act, const float* __restrict__ w2,
    const int* __restrict__ cnt, const int* __restrict__ offs,
    const int* __restrict__ toklist, const float* __restrict__ wlist,
    float* __restrict__ out)
{
    const int e  = blockIdx.z;
    const int c  = cnt[e];
    const int mt = blockIdx.y;
    if (mt * BM >= c) return;
    const int nt = blockIdx.x;              // 0..15 (D/64)
    const size_t slot0 = (size_t)offs[e] + (size_t)mt * BM;
    const int n0 = nt * BN;

    __shared__ __align__(16) unsigned short As[BM * LDP];
    __shared__ __align__(16) unsigned short Bs[BN * LDP];

    const int tid  = threadIdx.x;
    const int lane = tid & 63;
    const int wv   = tid >> 6;
    const int wm   = (wv & 1) * 64;
    const int wn   = (wv >> 1) * 32;
    const int quad = lane >> 4;
    const int r    = lane & 15;

    const int arow = tid >> 1;
    const int acol = (tid & 1) * 16;
    const unsigned short* Ag = act + (slot0 + arow) * FDIM + acol;
    unsigned short* Asw = As + arow * LDP + acol;
    const int brow = tid >> 2;
    const int bcol = (tid & 3) * 8;
    const float* Bg = w2 + ((size_t)e * DIM + n0 + brow) * FDIM + bcol;
    unsigned short* Bw = Bs + brow * LDP + bcol;

    f32x4_t acc[4][2];
#pragma unroll
    for (int i = 0; i < 4; ++i)
#pragma unroll
        for (int j = 0; j < 2; ++j) acc[i][j] = (f32x4_t){0.f, 0.f, 0.f, 0.f};

    uint4  a0 = *reinterpret_cast<const uint4*>(Ag);
    uint4  a1 = *reinterpret_cast<const uint4*>(Ag + 8);
    float4 p0 = *reinterpret_cast<const float4*>(Bg);
    float4 p1 = *reinterpret_cast<const float4*>(Bg + 4);

    for (int k0 = 0; k0 < FDIM; k0 += BK) {
        *reinterpret_cast<uint4*>(Asw)     = a0;
        *reinterpret_cast<uint4*>(Asw + 8) = a1;
        ushort4 q;
        q.x = f2bf(p0.x); q.y = f2bf(p0.y); q.z = f2bf(p0.z); q.w = f2bf(p0.w);
        *reinterpret_cast<ushort4*>(Bw)     = q;
        q.x = f2bf(p1.x); q.y = f2bf(p1.y); q.z = f2bf(p1.z); q.w = f2bf(p1.w);
        *reinterpret_cast<ushort4*>(Bw + 4) = q;
        __syncthreads();

        if (k0 + BK < FDIM) {
            a0 = *reinterpret_cast<const uint4*>(Ag + k0 + BK);
            a1 = *reinterpret_cast<const uint4*>(Ag + k0 + BK + 8);
            p0 = *reinterpret_cast<const float4*>(Bg + k0 + BK);
            p1 = *reinterpret_cast<const float4*>(Bg + k0 + BK + 4);
        }

        bf16x8_t af[4];
#pragma unroll
        for (int i = 0; i < 4; ++i)
            af[i] = *reinterpret_cast<const bf16x8_t*>(As + (wm + i * 16 + r) * LDP + quad * 8);
#pragma unroll
        for (int j = 0; j < 2; ++j) {
            bf16x8_t bf = *reinterpret_cast<const bf16x8_t*>(Bs + (wn + j * 16 + r) * LDP + quad * 8);
#pragma unroll
            for (int i = 0; i < 4; ++i)
                acc[i][j] = __builtin_amdgcn_mfma_f32_16x16x32_bf16(af[i], bf, acc[i][j], 0, 0, 0);
        }
        __syncthreads();
    }

    const int row0 = mt * BM;
#pragma unroll
    for (int i = 0; i < 4; ++i)
#pragma unroll
        for (int rr = 0; rr < 4; ++rr) {
            int m = wm + i * 16 + quad * 4 + rr;
            int row = row0 + m;
            if (row < c) {
                int tok  = toklist[e * T_TOK + row];
                float wt = wlist[e * T_TOK + row];
                float* orow = out + (size_t)tok * DIM + n0;
#pragma unroll
                for (int j = 0; j < 2; ++j) {
                    int n = wn + j * 16 + r;
                    atomicAdd(&orow[n], wt * acc[i][j][rr]);
                }
            }
        }
}

// ---------------------------------------------------------------------------
extern "C" void kernel_launch(void* const* d_in, const int* in_sizes, int n_in,
                              void* d_out, int out_size, void* d_ws, size_t ws_size,
                              hipStream_t stream)
{
    (void)in_sizes; (void)n_in; (void)out_size; (void)ws_size;
    const float* x  = (const float*)d_in[0];
    const float* gw = (const float*)d_in[1];
    const float* gb = (const float*)d_in[2];
    const float* w1 = (const float*)d_in[3];
    const float* w3 = (const float*)d_in[4];
    const float* w2 = (const float*)d_in[5];
    float* out = (float*)d_out;

    char* ws = (char*)d_ws;
    unsigned short* Xp  = (unsigned short*)ws;                       // 9216*1024*2
    unsigned short* act = (unsigned short*)(ws + 18874368);          // 9216*4096*2
    int*   cnt     = (int*)(ws + 18874368 + 75497472);
    int*   offs    = cnt + 64;
    int*   toklist = cnt + 128;
    float* wlist   = (float*)(cnt + 128 + NEXP * T_TOK);

    hipMemsetAsync(cnt, 0, 64, stream);
    hipMemsetAsync(out, 0, (size_t)T_TOK * DIM * sizeof(float), stream);

    gate_kernel<<<T_TOK / 4, 256, 0, stream>>>(x, gw, gb, cnt, toklist, wlist);
    offsets_kernel<<<1, 64, 0, stream>>>(cnt, offs);
    gather_kernel<<<NEXP * T_TOK, 256, 0, stream>>>(x, cnt, offs, toklist, Xp);
    stageA_kernel<<<dim3(FDIM / BN, T_TOK / BM, NEXP), 256, 0, stream>>>(Xp, w1, w3, cnt, offs, act);
    stageB_kernel<<<dim3(DIM / BN, T_TOK / BM, NEXP), 256, 0, stream>>>(act, w2, cnt, offs, toklist, wlist, out);
}